// Round 1
// baseline (1014.648 us; speedup 1.0000x reference)
//
#include <hip/hip_runtime.h>
#include <math.h>

#define Bn 8
#define NCn 384
#define Hn 32
#define Wn 32
#define Gn 6
#define GCn 64
#define HEADSn 12
#define Dn 32
#define HKn 15
#define WKn 15
#define NSn 225
#define NQn 1024
#define NKVn 900

__device__ __forceinline__ float gelu_f(float x) {
    return 0.5f * x * (1.0f + erff(x * 0.70710678118654752f));
}

// ---------------------------------------------------------------------------
// Kernel A: conv1x1 (256 -> 64) + GELU over the "concatenated" 4 maps.
// data[bg, c, hw] where gch = (bg%G)*256 + c indexes the concat of 4 maps.
// Output t1: (48, 64, 1024)
// ---------------------------------------------------------------------------
__global__ __launch_bounds__(256) void k_offconv1(
    const float* __restrict__ xr1, const float* __restrict__ xr2,
    const float* __restrict__ xx1, const float* __restrict__ xx2,
    const float* __restrict__ w1, const float* __restrict__ b1,
    float* __restrict__ t1)
{
    __shared__ float wt[64 * 68];   // wt[c_local][o], padded stride 68
    __shared__ float xs[64 * 64];   // xs[c_local][sp]
    const int bg  = blockIdx.y;     // 0..47
    const int spt = blockIdx.x;     // 0..15 (64 spatial each)
    const int b = bg / Gn, g = bg % Gn;
    const int tid = threadIdx.x;
    const int to = tid >> 4, ts = tid & 15;

    float acc[4][4] = {};

    for (int kc = 0; kc < 4; ++kc) {
        // stage weights: w1 is (64, 256) row-major; store transposed padded
        for (int idx = tid; idx < 4096; idx += 256) {
            int o = idx >> 6, cl = idx & 63;
            wt[cl * 68 + o] = w1[o * 256 + kc * 64 + cl];
        }
        // stage inputs: coalesced over spatial
        for (int idx = tid; idx < 4096; idx += 256) {
            int cl = idx >> 6, sp = idx & 63;
            int gch = g * 256 + kc * 64 + cl;     // 0..1535
            int m = gch / NCn, cm = gch % NCn;
            const float* img = (m == 0) ? xr1 : (m == 1) ? xr2 : (m == 2) ? xx1 : xx2;
            xs[cl * 64 + sp] = img[(b * NCn + cm) * NQn + spt * 64 + sp];
        }
        __syncthreads();
        #pragma unroll 8
        for (int c = 0; c < 64; ++c) {
            const float4 w4 = *(const float4*)&wt[c * 68 + to * 4];
            const float4 x4 = *(const float4*)&xs[c * 64 + ts * 4];
            const float wv[4] = {w4.x, w4.y, w4.z, w4.w};
            const float xv[4] = {x4.x, x4.y, x4.z, x4.w};
            #pragma unroll
            for (int i = 0; i < 4; ++i)
                #pragma unroll
                for (int j = 0; j < 4; ++j)
                    acc[i][j] += wv[i] * xv[j];
        }
        __syncthreads();
    }

    #pragma unroll
    for (int i = 0; i < 4; ++i) {
        int o = to * 4 + i;
        float bb = b1[o];
        float4 r;
        r.x = gelu_f(acc[i][0] + bb);
        r.y = gelu_f(acc[i][1] + bb);
        r.z = gelu_f(acc[i][2] + bb);
        r.w = gelu_f(acc[i][3] + bb);
        *(float4*)&t1[(bg * 64 + o) * NQn + spt * 64 + ts * 4] = r;
    }
}

// ---------------------------------------------------------------------------
// Kernel B: depthwise 3x3 stride2 + GELU + 1x1 (64->2) + tanh/scale + ref +
// clip -> pixel coords. One wave per (bg, hk, wk); lane = channel.
// posb: (48*225, 2) as (y_pix, x_pix)
// ---------------------------------------------------------------------------
__global__ __launch_bounds__(256) void k_offsets(
    const float* __restrict__ t1, const float* __restrict__ w2,
    const float* __restrict__ b2, const float* __restrict__ w3,
    float* __restrict__ posb)
{
    const int wid  = blockIdx.x * 4 + (threadIdx.x >> 6);   // 0..10799
    const int lane = threadIdx.x & 63;
    const int bg = wid / NSn, s = wid % NSn;
    const int hk = s / WKn, wk = s % WKn;

    const float* tp = t1 + (bg * 64 + lane) * NQn + (hk * 2) * Wn + wk * 2;
    const float* wp = w2 + lane * 9;
    float sv = b2[lane];
    #pragma unroll
    for (int i = 0; i < 3; ++i)
        #pragma unroll
        for (int j = 0; j < 3; ++j)
            sv += tp[i * Wn + j] * wp[i * 3 + j];
    float gv = gelu_f(sv);
    float ay = w3[lane] * gv;
    float ax = w3[64 + lane] * gv;
    #pragma unroll
    for (int off = 32; off > 0; off >>= 1) {
        ay += __shfl_xor(ay, off, 64);
        ax += __shfl_xor(ax, off, 64);
    }
    if (lane == 0) {
        float fy = tanhf(ay) * (2.0f / 14.0f);   // ORF * 1/(HK-1)
        float fx = tanhf(ax) * (2.0f / 14.0f);
        float cy = (float)(hk * 2 + 1) * (2.0f / 31.0f) - 1.0f;
        float cx = (float)(wk * 2 + 1) * (2.0f / 31.0f) - 1.0f;
        float py = fminf(fmaxf(fy + cy, -1.0f), 1.0f);
        float px = fminf(fmaxf(fx + cx, -1.0f), 1.0f);
        posb[wid * 2 + 0] = (py + 1.0f) * 0.5f * 31.0f;
        posb[wid * 2 + 1] = (px + 1.0f) * 0.5f * 31.0f;
    }
}

// ---------------------------------------------------------------------------
// Kernel C: bilinear sampling of the 4 maps -> sampled (8, 384, 900)
// block = (bg, map); threads loop over 64 channels x 225 samples
// ---------------------------------------------------------------------------
__global__ __launch_bounds__(256) void k_sample(
    const float* __restrict__ xr1, const float* __restrict__ xr2,
    const float* __restrict__ xx1, const float* __restrict__ xx2,
    const float* __restrict__ posb, float* __restrict__ smp)
{
    const int bg = blockIdx.x;     // 0..47
    const int m  = blockIdx.y;     // 0..3
    const int b = bg / Gn, g = bg % Gn;
    const float* img = (m == 0) ? xr1 : (m == 1) ? xr2 : (m == 2) ? xx1 : xx2;

    for (int idx = threadIdx.x; idx < 64 * NSn; idx += 256) {
        int c = idx / NSn, s = idx - c * NSn;
        float py = posb[(bg * NSn + s) * 2 + 0];
        float px = posb[(bg * NSn + s) * 2 + 1];
        float y0f = floorf(py), x0f = floorf(px);
        float wy = py - y0f, wx = px - x0f;
        int y0 = (int)y0f, x0 = (int)x0f;
        int y1 = min(y0 + 1, Hn - 1), x1 = min(x0 + 1, Wn - 1);
        const float* base = img + (b * NCn + g * GCn + c) * NQn;
        float v00 = base[y0 * Wn + x0], v01 = base[y0 * Wn + x1];
        float v10 = base[y1 * Wn + x0], v11 = base[y1 * Wn + x1];
        float v = v00 * (1.0f - wy) * (1.0f - wx) + v01 * (1.0f - wy) * wx
                + v10 * wy * (1.0f - wx) + v11 * wy * wx;
        smp[(b * NCn + g * GCn + c) * NKVn + m * NSn + s] = v;
    }
}

// ---------------------------------------------------------------------------
// Kernel D: batched conv1x1 GEMM, Cin = Cout = 384.
// Y[b,o,n] = sum_c W[o,c] X[b,c,n] + bias[o] (+ resid[b,o,n])
// tile 64(o) x 64(n), 4x4 micro-tile
// ---------------------------------------------------------------------------
__global__ __launch_bounds__(256) void k_conv1x1(
    const float* __restrict__ X, const float* __restrict__ W,
    const float* __restrict__ bias, const float* __restrict__ resid,
    float* __restrict__ Y, int N)
{
    __shared__ float wt[64 * 68];
    __shared__ float xs[64 * 64];
    const int nt = blockIdx.x, ot = blockIdx.y, b = blockIdx.z;
    const int tid = threadIdx.x;
    const int to = tid >> 4, ts = tid & 15;

    float acc[4][4] = {};

    for (int kc = 0; kc < 6; ++kc) {
        for (int idx = tid; idx < 4096; idx += 256) {
            int o = idx >> 6, cl = idx & 63;
            wt[cl * 68 + o] = W[(ot * 64 + o) * NCn + kc * 64 + cl];
        }
        for (int idx = tid; idx < 4096; idx += 256) {
            int cl = idx >> 6, nl = idx & 63;
            int n = nt * 64 + nl;
            xs[cl * 64 + nl] = (n < N) ? X[((size_t)b * NCn + kc * 64 + cl) * N + n] : 0.0f;
        }
        __syncthreads();
        #pragma unroll 8
        for (int c = 0; c < 64; ++c) {
            const float4 w4 = *(const float4*)&wt[c * 68 + to * 4];
            const float4 x4 = *(const float4*)&xs[c * 64 + ts * 4];
            const float wv[4] = {w4.x, w4.y, w4.z, w4.w};
            const float xv[4] = {x4.x, x4.y, x4.z, x4.w};
            #pragma unroll
            for (int i = 0; i < 4; ++i)
                #pragma unroll
                for (int j = 0; j < 4; ++j)
                    acc[i][j] += wv[i] * xv[j];
        }
        __syncthreads();
    }

    #pragma unroll
    for (int i = 0; i < 4; ++i) {
        int o = ot * 64 + to * 4 + i;
        float bb = bias[o];
        #pragma unroll
        for (int j = 0; j < 4; ++j) {
            int n = nt * 64 + ts * 4 + j;
            if (n < N) {
                float v = acc[i][j] + bb;
                if (resid) v += resid[((size_t)b * NCn + o) * N + n];
                Y[((size_t)b * NCn + o) * N + n] = v;
            }
        }
    }
}

// ---------------------------------------------------------------------------
// Kernel E: fused flash attention.
// q: (B,384,1024), k/v: (B,384,900); head h = channels h*32..h*32+31
// block = (mt, h, b): 64 queries, stream keys in chunks of 64
// ---------------------------------------------------------------------------
__global__ __launch_bounds__(256) void k_attn(
    const float* __restrict__ qb, const float* __restrict__ kb,
    const float* __restrict__ vb, float* __restrict__ outp)
{
    __shared__ float qs[32 * 64];
    __shared__ float ks[32 * 64];
    __shared__ float vs[32 * 64];
    __shared__ float ps[64 * 68];
    const int mt = blockIdx.x, h = blockIdx.y, b = blockIdx.z;
    const int tid = threadIdx.x;
    const int tm = tid >> 4, tn = tid & 15;
    const float scale = 0.17677669529663687f;   // 1/sqrt(32)

    for (int idx = tid; idx < 2048; idx += 256) {
        int d = idx >> 6, ml = idx & 63;
        qs[d * 64 + ml] = qb[((size_t)(b * HEADSn + h) * Dn + d) * NQn + mt * 64 + ml] * scale;
    }

    float mrun[4], lrun[4], oacc[4][2];
    #pragma unroll
    for (int i = 0; i < 4; ++i) {
        mrun[i] = -1e30f; lrun[i] = 0.0f; oacc[i][0] = 0.0f; oacc[i][1] = 0.0f;
    }

    for (int nc = 0; nc < 15; ++nc) {
        const int n0 = nc * 64;
        for (int idx = tid; idx < 2048; idx += 256) {
            int d = idx >> 6, nl = idx & 63;
            int n = n0 + nl;
            float kv = 0.0f, vv = 0.0f;
            if (n < NKVn) {
                kv = kb[((size_t)(b * HEADSn + h) * Dn + d) * NKVn + n];
                vv = vb[((size_t)(b * HEADSn + h) * Dn + d) * NKVn + n];
            }
            ks[d * 64 + nl] = kv;
            vs[d * 64 + nl] = vv;
        }
        __syncthreads();

        float s[4][4] = {};
        #pragma unroll 8
        for (int d = 0; d < 32; ++d) {
            const float4 q4 = *(const float4*)&qs[d * 64 + tm * 4];
            const float4 k4 = *(const float4*)&ks[d * 64 + tn * 4];
            const float qv[4] = {q4.x, q4.y, q4.z, q4.w};
            const float kv[4] = {k4.x, k4.y, k4.z, k4.w};
            #pragma unroll
            for (int i = 0; i < 4; ++i)
                #pragma unroll
                for (int j = 0; j < 4; ++j)
                    s[i][j] += qv[i] * kv[j];
        }
        if (n0 + 64 > NKVn) {
            #pragma unroll
            for (int j = 0; j < 4; ++j)
                if (n0 + tn * 4 + j >= NKVn) {
                    #pragma unroll
                    for (int i = 0; i < 4; ++i) s[i][j] = -1e30f;
                }
        }

        #pragma unroll
        for (int i = 0; i < 4; ++i) {
            float rmax = fmaxf(fmaxf(s[i][0], s[i][1]), fmaxf(s[i][2], s[i][3]));
            rmax = fmaxf(rmax, __shfl_xor(rmax, 1, 64));
            rmax = fmaxf(rmax, __shfl_xor(rmax, 2, 64));
            rmax = fmaxf(rmax, __shfl_xor(rmax, 4, 64));
            rmax = fmaxf(rmax, __shfl_xor(rmax, 8, 64));
            float mnew  = fmaxf(mrun[i], rmax);
            float alpha = __expf(mrun[i] - mnew);
            float p0 = __expf(s[i][0] - mnew);
            float p1 = __expf(s[i][1] - mnew);
            float p2 = __expf(s[i][2] - mnew);
            float p3 = __expf(s[i][3] - mnew);
            float rsum = p0 + p1 + p2 + p3;
            rsum += __shfl_xor(rsum, 1, 64);
            rsum += __shfl_xor(rsum, 2, 64);
            rsum += __shfl_xor(rsum, 4, 64);
            rsum += __shfl_xor(rsum, 8, 64);
            lrun[i] = lrun[i] * alpha + rsum;
            mrun[i] = mnew;
            oacc[i][0] *= alpha;
            oacc[i][1] *= alpha;
            *(float4*)&ps[(tm * 4 + i) * 68 + tn * 4] = make_float4(p0, p1, p2, p3);
        }
        __syncthreads();

        #pragma unroll 4
        for (int n = 0; n < 64; n += 4) {
            const float4 v0 = *(const float4*)&vs[(tn * 2 + 0) * 64 + n];
            const float4 v1 = *(const float4*)&vs[(tn * 2 + 1) * 64 + n];
            #pragma unroll
            for (int i = 0; i < 4; ++i) {
                const float4 p4 = *(const float4*)&ps[(tm * 4 + i) * 68 + n];
                oacc[i][0] += p4.x * v0.x + p4.y * v0.y + p4.z * v0.z + p4.w * v0.w;
                oacc[i][1] += p4.x * v1.x + p4.y * v1.y + p4.z * v1.z + p4.w * v1.w;
            }
        }
        __syncthreads();
    }

    #pragma unroll
    for (int i = 0; i < 4; ++i) {
        float inv_l = 1.0f / lrun[i];
        #pragma unroll
        for (int jd = 0; jd < 2; ++jd) {
            int d = tn * 2 + jd;
            outp[((size_t)(b * HEADSn + h) * Dn + d) * NQn + mt * 64 + tm * 4 + i] =
                oacc[i][jd] * inv_l;
        }
    }
}

// ---------------------------------------------------------------------------
extern "C" void kernel_launch(void* const* d_in, const int* in_sizes, int n_in,
                              void* d_out, int out_size, void* d_ws, size_t ws_size,
                              hipStream_t stream) {
    const float* query = (const float*)d_in[0];
    const float* xr1   = (const float*)d_in[1];
    const float* xr2   = (const float*)d_in[2];
    const float* xx1   = (const float*)d_in[3];
    const float* xx2   = (const float*)d_in[4];
    const float* w1    = (const float*)d_in[5];
    const float* b1    = (const float*)d_in[6];
    const float* w2    = (const float*)d_in[7];
    const float* b2    = (const float*)d_in[8];
    const float* w3    = (const float*)d_in[9];
    const float* q_w   = (const float*)d_in[10];
    const float* q_b   = (const float*)d_in[11];
    const float* k_w   = (const float*)d_in[12];
    const float* k_b   = (const float*)d_in[13];
    const float* v_w   = (const float*)d_in[14];
    const float* v_b   = (const float*)d_in[15];
    const float* o_w   = (const float*)d_in[16];
    const float* o_b   = (const float*)d_in[17];
    float* out = (float*)d_out;

    // workspace layout (floats)
    float* ws   = (float*)d_ws;
    float* t1   = ws;                       // 48*64*1024   = 3,145,728
    float* posb = t1 + 3145728;             // 10800*2      = 21,600
    float* smp  = posb + 21600;             // 8*384*900    = 2,764,800
    float* qbuf = smp + 2764800;            // 8*384*1024   = 3,145,728
    float* kbuf = qbuf + 3145728;           // 8*384*900    = 2,764,800
    float* vbuf = kbuf + 2764800;           // 8*384*900    = 2,764,800
    float* aout = t1;                       // reuse: t1 dead after k_offsets

    k_offconv1<<<dim3(16, 48), 256, 0, stream>>>(xr1, xr2, xx1, xx2, w1, b1, t1);
    k_offsets<<<dim3(2700), 256, 0, stream>>>(t1, w2, b2, w3, posb);
    k_sample<<<dim3(48, 4), 256, 0, stream>>>(xr1, xr2, xx1, xx2, posb, smp);
    k_conv1x1<<<dim3(16, 6, Bn), 256, 0, stream>>>(query, q_w, q_b, nullptr, qbuf, NQn);
    k_conv1x1<<<dim3(15, 6, Bn), 256, 0, stream>>>(smp, k_w, k_b, nullptr, kbuf, NKVn);
    k_conv1x1<<<dim3(15, 6, Bn), 256, 0, stream>>>(smp, v_w, v_b, nullptr, vbuf, NKVn);
    k_attn<<<dim3(16, HEADSn, Bn), 256, 0, stream>>>(qbuf, kbuf, vbuf, aout);
    k_conv1x1<<<dim3(16, 6, Bn), 256, 0, stream>>>(aout, o_w, o_b, query, out, NQn);
}

// Round 2
// 471.514 us; speedup vs baseline: 2.1519x; 2.1519x over previous
//
#include <hip/hip_runtime.h>
#include <math.h>

#define Bn 8
#define NCn 384
#define Hn 32
#define Wn 32
#define Gn 6
#define GCn 64
#define HEADSn 12
#define Dn 32
#define HKn 15
#define WKn 15
#define NSn 225
#define NQn 1024
#define NKVn 900
#define VSTRIDE 912   // V row stride in bf16 elements (multiple of 8 -> 16B frag alignment)

typedef __attribute__((ext_vector_type(8))) short short8;
typedef __attribute__((ext_vector_type(4))) float floatx4;

__device__ __forceinline__ float gelu_f(float x) {
    return 0.5f * x * (1.0f + erff(x * 0.70710678118654752f));
}

__device__ __forceinline__ ushort f2bf(float x) {
    unsigned u = __float_as_uint(x);
    u = (u + 0x7FFF + ((u >> 16) & 1)) >> 16;   // RNE
    return (ushort)u;
}

// ---------------------------------------------------------------------------
// Kernel A: conv1x1 (256 -> 64) + GELU over the "concatenated" 4 maps.
// ---------------------------------------------------------------------------
__global__ __launch_bounds__(256) void k_offconv1(
    const float* __restrict__ xr1, const float* __restrict__ xr2,
    const float* __restrict__ xx1, const float* __restrict__ xx2,
    const float* __restrict__ w1, const float* __restrict__ b1,
    float* __restrict__ t1)
{
    __shared__ float wt[64 * 68];
    __shared__ float xs[64 * 64];
    const int bg  = blockIdx.y;
    const int spt = blockIdx.x;
    const int b = bg / Gn, g = bg % Gn;
    const int tid = threadIdx.x;
    const int to = tid >> 4, ts = tid & 15;

    float acc[4][4] = {};

    for (int kc = 0; kc < 4; ++kc) {
        for (int idx = tid; idx < 4096; idx += 256) {
            int o = idx >> 6, cl = idx & 63;
            wt[cl * 68 + o] = w1[o * 256 + kc * 64 + cl];
        }
        for (int idx = tid; idx < 4096; idx += 256) {
            int cl = idx >> 6, sp = idx & 63;
            int gch = g * 256 + kc * 64 + cl;
            int m = gch / NCn, cm = gch % NCn;
            const float* img = (m == 0) ? xr1 : (m == 1) ? xr2 : (m == 2) ? xx1 : xx2;
            xs[cl * 64 + sp] = img[(b * NCn + cm) * NQn + spt * 64 + sp];
        }
        __syncthreads();
        #pragma unroll 8
        for (int c = 0; c < 64; ++c) {
            const float4 w4 = *(const float4*)&wt[c * 68 + to * 4];
            const float4 x4 = *(const float4*)&xs[c * 64 + ts * 4];
            const float wv[4] = {w4.x, w4.y, w4.z, w4.w};
            const float xv[4] = {x4.x, x4.y, x4.z, x4.w};
            #pragma unroll
            for (int i = 0; i < 4; ++i)
                #pragma unroll
                for (int j = 0; j < 4; ++j)
                    acc[i][j] += wv[i] * xv[j];
        }
        __syncthreads();
    }

    #pragma unroll
    for (int i = 0; i < 4; ++i) {
        int o = to * 4 + i;
        float bb = b1[o];
        float4 r;
        r.x = gelu_f(acc[i][0] + bb);
        r.y = gelu_f(acc[i][1] + bb);
        r.z = gelu_f(acc[i][2] + bb);
        r.w = gelu_f(acc[i][3] + bb);
        *(float4*)&t1[(bg * 64 + o) * NQn + spt * 64 + ts * 4] = r;
    }
}

// ---------------------------------------------------------------------------
// Kernel B: depthwise 3x3 stride2 + GELU + 1x1 (64->2) + tanh -> pixel coords
// ---------------------------------------------------------------------------
__global__ __launch_bounds__(256) void k_offsets(
    const float* __restrict__ t1, const float* __restrict__ w2,
    const float* __restrict__ b2, const float* __restrict__ w3,
    float* __restrict__ posb)
{
    const int wid  = blockIdx.x * 4 + (threadIdx.x >> 6);
    const int lane = threadIdx.x & 63;
    const int bg = wid / NSn, s = wid % NSn;
    const int hk = s / WKn, wk = s % WKn;

    const float* tp = t1 + (bg * 64 + lane) * NQn + (hk * 2) * Wn + wk * 2;
    const float* wp = w2 + lane * 9;
    float sv = b2[lane];
    #pragma unroll
    for (int i = 0; i < 3; ++i)
        #pragma unroll
        for (int j = 0; j < 3; ++j)
            sv += tp[i * Wn + j] * wp[i * 3 + j];
    float gv = gelu_f(sv);
    float ay = w3[lane] * gv;
    float ax = w3[64 + lane] * gv;
    #pragma unroll
    for (int off = 32; off > 0; off >>= 1) {
        ay += __shfl_xor(ay, off, 64);
        ax += __shfl_xor(ax, off, 64);
    }
    if (lane == 0) {
        float fy = tanhf(ay) * (2.0f / 14.0f);
        float fx = tanhf(ax) * (2.0f / 14.0f);
        float cy = (float)(hk * 2 + 1) * (2.0f / 31.0f) - 1.0f;
        float cx = (float)(wk * 2 + 1) * (2.0f / 31.0f) - 1.0f;
        float py = fminf(fmaxf(fy + cy, -1.0f), 1.0f);
        float px = fminf(fmaxf(fx + cx, -1.0f), 1.0f);
        posb[wid * 2 + 0] = (py + 1.0f) * 0.5f * 31.0f;
        posb[wid * 2 + 1] = (px + 1.0f) * 0.5f * 31.0f;
    }
}

// ---------------------------------------------------------------------------
// Kernel C: bilinear sampling of the 4 maps -> sampled (8, 384, 900)
// ---------------------------------------------------------------------------
__global__ __launch_bounds__(256) void k_sample(
    const float* __restrict__ xr1, const float* __restrict__ xr2,
    const float* __restrict__ xx1, const float* __restrict__ xx2,
    const float* __restrict__ posb, float* __restrict__ smp)
{
    const int bg = blockIdx.x;
    const int m  = blockIdx.y;
    const int b = bg / Gn, g = bg % Gn;
    const float* img = (m == 0) ? xr1 : (m == 1) ? xr2 : (m == 2) ? xx1 : xx2;

    for (int idx = threadIdx.x; idx < 64 * NSn; idx += 256) {
        int c = idx / NSn, s = idx - c * NSn;
        float py = posb[(bg * NSn + s) * 2 + 0];
        float px = posb[(bg * NSn + s) * 2 + 1];
        float y0f = floorf(py), x0f = floorf(px);
        float wy = py - y0f, wx = px - x0f;
        int y0 = (int)y0f, x0 = (int)x0f;
        int y1 = min(y0 + 1, Hn - 1), x1 = min(x0 + 1, Wn - 1);
        const float* base = img + (b * NCn + g * GCn + c) * NQn;
        float v00 = base[y0 * Wn + x0], v01 = base[y0 * Wn + x1];
        float v10 = base[y1 * Wn + x0], v11 = base[y1 * Wn + x1];
        float v = v00 * (1.0f - wy) * (1.0f - wx) + v01 * (1.0f - wy) * wx
                + v10 * wy * (1.0f - wx) + v11 * wy * wx;
        smp[(b * NCn + g * GCn + c) * NKVn + m * NSn + s] = v;
    }
}

// ---------------------------------------------------------------------------
// Kernel D: batched conv1x1 GEMM, Cin = Cout = 384.
// mode 0: fp32 (b,384,N) [+resid]
// mode 1: bf16 (b,384,VSTRIDE) d-major          (for V)
// mode 2: bf16 (b,12,N,32)    seq-major         (for Q,K: MFMA-frag friendly)
// ---------------------------------------------------------------------------
__global__ __launch_bounds__(256) void k_conv1x1(
    const float* __restrict__ X, const float* __restrict__ W,
    const float* __restrict__ bias, const float* __restrict__ resid,
    float* __restrict__ Yf, ushort* __restrict__ Yh,
    int N, int mode)
{
    __shared__ float wt[64 * 68];
    __shared__ float xs[64 * 64];
    const int nt = blockIdx.x, ot = blockIdx.y, b = blockIdx.z;
    const int tid = threadIdx.x;
    const int to = tid >> 4, ts = tid & 15;

    float acc[4][4] = {};

    for (int kc = 0; kc < 6; ++kc) {
        for (int idx = tid; idx < 4096; idx += 256) {
            int o = idx >> 6, cl = idx & 63;
            wt[cl * 68 + o] = W[(ot * 64 + o) * NCn + kc * 64 + cl];
        }
        for (int idx = tid; idx < 4096; idx += 256) {
            int cl = idx >> 6, nl = idx & 63;
            int n = nt * 64 + nl;
            xs[cl * 64 + nl] = (n < N) ? X[((size_t)b * NCn + kc * 64 + cl) * N + n] : 0.0f;
        }
        __syncthreads();
        #pragma unroll 8
        for (int c = 0; c < 64; ++c) {
            const float4 w4 = *(const float4*)&wt[c * 68 + to * 4];
            const float4 x4 = *(const float4*)&xs[c * 64 + ts * 4];
            const float wv[4] = {w4.x, w4.y, w4.z, w4.w};
            const float xv[4] = {x4.x, x4.y, x4.z, x4.w};
            #pragma unroll
            for (int i = 0; i < 4; ++i)
                #pragma unroll
                for (int j = 0; j < 4; ++j)
                    acc[i][j] += wv[i] * xv[j];
        }
        __syncthreads();
    }

    const int o0 = ot * 64 + to * 4;
    const int n0 = nt * 64 + ts * 4;

    if (mode == 0) {
        #pragma unroll
        for (int i = 0; i < 4; ++i) {
            float bb = bias[o0 + i];
            #pragma unroll
            for (int j = 0; j < 4; ++j) {
                int n = n0 + j;
                if (n < N) {
                    float v = acc[i][j] + bb;
                    if (resid) v += resid[((size_t)b * NCn + o0 + i) * N + n];
                    Yf[((size_t)b * NCn + o0 + i) * N + n] = v;
                }
            }
        }
    } else if (mode == 1) {
        // bf16 d-major, padded row stride
        #pragma unroll
        for (int i = 0; i < 4; ++i) {
            float bb = bias[o0 + i];
            size_t base = ((size_t)b * NCn + o0 + i) * VSTRIDE + n0;
            if (n0 + 3 < N) {
                ushort4 r;
                r.x = f2bf(acc[i][0] + bb); r.y = f2bf(acc[i][1] + bb);
                r.z = f2bf(acc[i][2] + bb); r.w = f2bf(acc[i][3] + bb);
                *(ushort4*)(Yh + base) = r;
            } else {
                #pragma unroll
                for (int j = 0; j < 4; ++j)
                    if (n0 + j < N) Yh[base + j] = f2bf(acc[i][j] + bb);
            }
        }
    } else {
        // bf16 transposed: (b, head, n, d); o0 is 4-aligned, never crosses head
        const int head = o0 >> 5, d0 = o0 & 31;
        float bb[4];
        #pragma unroll
        for (int i = 0; i < 4; ++i) bb[i] = bias[o0 + i];
        #pragma unroll
        for (int j = 0; j < 4; ++j) {
            int n = n0 + j;
            if (n < N) {
                ushort4 r;
                r.x = f2bf(acc[0][j] + bb[0]); r.y = f2bf(acc[1][j] + bb[1]);
                r.z = f2bf(acc[2][j] + bb[2]); r.w = f2bf(acc[3][j] + bb[3]);
                *(ushort4*)(Yh + ((size_t)(b * HEADSn + head) * N + n) * 32 + d0) = r;
            }
        }
    }
}

// ---------------------------------------------------------------------------
// Kernel E: flash attention with bf16 MFMA (16x16x32).
// qT: (b,12,1024,32) bf16   kT: (b,12,900,32) bf16   vb: (b,384,VSTRIDE) bf16
// out: (b,384,1024) fp32
// Block: 4 waves; wave w handles 16 queries. 64-key chunks.
// Scores are small (sigma~0.15) -> exp without max subtraction is safe.
// ---------------------------------------------------------------------------
__global__ __launch_bounds__(256) void k_attn_mfma(
    const ushort* __restrict__ qT, const ushort* __restrict__ kT,
    const ushort* __restrict__ vb, float* __restrict__ outp)
{
    __shared__ __align__(16) char smem[10240];   // P: 4 waves x 16 x 80 bf16; reused for O transpose
    const int mt = blockIdx.x, h = blockIdx.y, b = blockIdx.z;
    const int tid = threadIdx.x;
    const int w = tid >> 6, lane = tid & 63;
    const int l16 = lane & 15, quad = lane >> 4;
    const int bh = b * HEADSn + h;
    const float scale = 0.17677669529663687f;

    ushort* p_w = (ushort*)smem + w * (16 * 80);

    // A-frag of Q: A[m=l16][k=quad*8+j], queries mt*64 + w*16 + l16
    const short8 qf = *(const short8*)(qT +
        (size_t)((bh * NQn + mt * 64 + w * 16 + l16) * 32 + quad * 8));

    floatx4 zero = {0.0f, 0.0f, 0.0f, 0.0f};
    floatx4 oacc[2] = {zero, zero};
    float lrun[4] = {0.0f, 0.0f, 0.0f, 0.0f};

    const ushort* kbase = kT + (size_t)bh * NKVn * 32;
    const ushort* vbase = vb + ((size_t)b * NCn + h * Dn) * VSTRIDE;

    for (int nc = 0; nc < 15; ++nc) {
        const int n0 = nc * 64;
        floatx4 sf[4];
        #pragma unroll
        for (int t = 0; t < 4; ++t) {
            // B-frag of K: B[k=quad*8+j][n=l16], key = n0 + t*16 + l16
            const short8 kf = *(const short8*)(kbase +
                (size_t)((n0 + t * 16 + l16) * 32 + quad * 8));
            sf[t] = __builtin_amdgcn_mfma_f32_16x16x32_bf16(qf, kf, zero, 0, 0, 0);
        }
        const int limit = NKVn - n0;   // valid keys this chunk
        #pragma unroll
        for (int t = 0; t < 4; ++t) {
            const int col = t * 16 + l16;
            #pragma unroll
            for (int r = 0; r < 4; ++r) {
                float p = (col < limit) ? __expf(sf[t][r] * scale) : 0.0f;
                lrun[r] += p;
                p_w[(quad * 4 + r) * 80 + col] = f2bf(p);   // C-layout -> LDS
            }
        }
        // same-wave LDS RAW: compiler inserts lgkmcnt wait; no barrier needed
        #pragma unroll
        for (int kc = 0; kc < 2; ++kc) {
            // A-frag of P: A[m=l16][k=quad*8+j], key chunk kc*32
            const short8 pf = *(const short8*)(p_w + l16 * 80 + kc * 32 + quad * 8);
            #pragma unroll
            for (int nt2 = 0; nt2 < 2; ++nt2) {
                // B-frag of V^T: B[k=key][n=dim], from d-major V rows
                const short8 vf = *(const short8*)(vbase +
                    (size_t)((nt2 * 16 + l16) * VSTRIDE + n0 + kc * 32 + quad * 8));
                oacc[nt2] = __builtin_amdgcn_mfma_f32_16x16x32_bf16(pf, vf, oacc[nt2], 0, 0, 0);
            }
        }
    }

    // row-wise softmax denominators: reduce over the 16 lanes of each quad
    #pragma unroll
    for (int r = 0; r < 4; ++r) {
        float l = lrun[r];
        l += __shfl_xor(l, 1, 64);
        l += __shfl_xor(l, 2, 64);
        l += __shfl_xor(l, 4, 64);
        l += __shfl_xor(l, 8, 64);
        lrun[r] = 1.0f / l;
    }
    #pragma unroll
    for (int nt2 = 0; nt2 < 2; ++nt2)
        #pragma unroll
        for (int r = 0; r < 4; ++r)
            oacc[nt2][r] *= lrun[r];

    // transpose O through LDS for coalesced d-major store
    __syncthreads();
    float* o_lds = (float*)smem;   // [32][66]
    #pragma unroll
    for (int nt2 = 0; nt2 < 2; ++nt2)
        #pragma unroll
        for (int r = 0; r < 4; ++r)
            o_lds[(nt2 * 16 + l16) * 66 + w * 16 + quad * 4 + r] = oacc[nt2][r];
    __syncthreads();
    for (int idx = tid; idx < 2048; idx += 256) {
        int d = idx >> 6, m = idx & 63;
        outp[((size_t)(b * NCn + h * Dn + d)) * NQn + mt * 64 + m] = o_lds[d * 66 + m];
    }
}

// ---------------------------------------------------------------------------
extern "C" void kernel_launch(void* const* d_in, const int* in_sizes, int n_in,
                              void* d_out, int out_size, void* d_ws, size_t ws_size,
                              hipStream_t stream) {
    const float* query = (const float*)d_in[0];
    const float* xr1   = (const float*)d_in[1];
    const float* xr2   = (const float*)d_in[2];
    const float* xx1   = (const float*)d_in[3];
    const float* xx2   = (const float*)d_in[4];
    const float* w1    = (const float*)d_in[5];
    const float* b1    = (const float*)d_in[6];
    const float* w2    = (const float*)d_in[7];
    const float* b2    = (const float*)d_in[8];
    const float* w3    = (const float*)d_in[9];
    const float* q_w   = (const float*)d_in[10];
    const float* q_b   = (const float*)d_in[11];
    const float* k_w   = (const float*)d_in[12];
    const float* k_b   = (const float*)d_in[13];
    const float* v_w   = (const float*)d_in[14];
    const float* v_b   = (const float*)d_in[15];
    const float* o_w   = (const float*)d_in[16];
    const float* o_b   = (const float*)d_in[17];
    float* out = (float*)d_out;

    // workspace layout (float units; all 16B aligned)
    float* ws    = (float*)d_ws;
    float*  t1   = ws;                           // 48*64*1024      = 3,145,728 f
    float*  posb = t1 + 3145728;                 // 21,600 -> pad 21,632
    float*  smp  = posb + 21632;                 // 8*384*900       = 2,764,800 f
    ushort* qTb  = (ushort*)(smp + 2764800);     // 8*12*1024*32    = 3,145,728 u (1,572,864 f)
    ushort* kTb  = (ushort*)((float*)qTb + 1572864);   // 8*12*900*32 = 2,764,800 u (1,382,400 f)
    ushort* vTb  = (ushort*)((float*)kTb + 1382400);   // 8*384*912   = 2,801,664 u (1,400,832 f)
    // + slack after vTb for masked OOB fragment reads (poison 0xAAAA = tiny bf16, never NaN)
    float*  aout = t1;   // t1 dead after k_offsets

    k_offconv1<<<dim3(16, 48), 256, 0, stream>>>(xr1, xr2, xx1, xx2, w1, b1, t1);
    k_offsets<<<dim3(2700), 256, 0, stream>>>(t1, w2, b2, w3, posb);
    k_sample<<<dim3(48, 4), 256, 0, stream>>>(xr1, xr2, xx1, xx2, posb, smp);
    k_conv1x1<<<dim3(16, 6, Bn), 256, 0, stream>>>(query, q_w, q_b, nullptr, nullptr, qTb, NQn, 2);
    k_conv1x1<<<dim3(15, 6, Bn), 256, 0, stream>>>(smp, k_w, k_b, nullptr, nullptr, kTb, NKVn, 2);
    k_conv1x1<<<dim3(15, 6, Bn), 256, 0, stream>>>(smp, v_w, v_b, nullptr, nullptr, vTb, NKVn, 1);
    k_attn_mfma<<<dim3(16, HEADSn, Bn), 256, 0, stream>>>(qTb, kTb, vTb, aout);
    k_conv1x1<<<dim3(16, 6, Bn), 256, 0, stream>>>(aout, o_w, o_b, query, out, nullptr, NQn, 0);
}

// Round 4
// 384.961 us; speedup vs baseline: 2.6357x; 1.2248x over previous
//
#include <hip/hip_runtime.h>
#include <math.h>

#define Bn 8
#define NCn 384
#define Hn 32
#define Wn 32
#define Gn 6
#define GCn 64
#define HEADSn 12
#define Dn 32
#define HKn 15
#define WKn 15
#define NSn 225
#define NQn 1024
#define NKVn 900
#define VSTRIDE 960   // V row stride in bf16; covers max frag read (key 952+8) so
                      // no read leaves the row; keys 900..959 zero-filled.

typedef __attribute__((ext_vector_type(8))) short short8;
typedef __attribute__((ext_vector_type(4))) float floatx4;

__device__ __forceinline__ float gelu_f(float x) {
    return 0.5f * x * (1.0f + erff(x * 0.70710678118654752f));
}

__device__ __forceinline__ ushort f2bf(float x) {
    unsigned u = __float_as_uint(x);
    u = (u + 0x7FFF + ((u >> 16) & 1)) >> 16;   // RNE
    return (ushort)u;
}

// ---------------------------------------------------------------------------
// Convert all weight matrices to bf16 (once per call; cheap).
// wb: w1b[16384] | qwb[147456] | kwb[147456] | vwb[147456] | owb[147456]
// ---------------------------------------------------------------------------
__global__ __launch_bounds__(256) void k_cvtw(
    const float* __restrict__ w1, const float* __restrict__ qw,
    const float* __restrict__ kw, const float* __restrict__ vw,
    const float* __restrict__ ow, ushort* __restrict__ wb)
{
    int i = blockIdx.x * 256 + threadIdx.x;
    if (i >= 606208) return;
    float v;
    if      (i < 16384)  v = w1[i];
    else if (i < 163840) v = qw[i - 16384];
    else if (i < 311296) v = kw[i - 163840];
    else if (i < 458752) v = vw[i - 311296];
    else                 v = ow[i - 458752];
    wb[i] = f2bf(v);
}

// ---------------------------------------------------------------------------
// Build dataT (48, 1024, 256) bf16: n-major, c-contiguous view of the
// 4-map concat split into groups. LDS-transposed 64x64 tiles.
// ---------------------------------------------------------------------------
__global__ __launch_bounds__(256) void k_transpose4(
    const float* __restrict__ xr1, const float* __restrict__ xr2,
    const float* __restrict__ xx1, const float* __restrict__ xx2,
    ushort* __restrict__ dataT)
{
    __shared__ float lds[64 * 65];
    const int hwt = blockIdx.x;   // 0..15
    const int bg  = blockIdx.y;   // 0..47
    const int b = bg / Gn, g = bg % Gn;
    const int tid = threadIdx.x;

    for (int kc = 0; kc < 4; ++kc) {
        for (int idx = tid; idx < 4096; idx += 256) {
            int cl = idx >> 6, hwl = idx & 63;
            int gch = g * 256 + kc * 64 + cl;
            int m = gch / NCn, cm = gch % NCn;
            const float* img = (m == 0) ? xr1 : (m == 1) ? xr2 : (m == 2) ? xx1 : xx2;
            lds[cl * 65 + hwl] = img[(b * NCn + cm) * NQn + hwt * 64 + hwl];
        }
        __syncthreads();
        for (int idx = tid; idx < 4096; idx += 256) {
            int hwl = idx >> 6, cl = idx & 63;
            dataT[((size_t)bg * NQn + hwt * 64 + hwl) * 256 + kc * 64 + cl] =
                f2bf(lds[cl * 65 + hwl]);
        }
        __syncthreads();
    }
}

// ---------------------------------------------------------------------------
// Build qXT (8, 1024, 384) bf16 from query (8, 384, 1024) fp32.
// ---------------------------------------------------------------------------
__global__ __launch_bounds__(256) void k_transposeQ(
    const float* __restrict__ query, ushort* __restrict__ qXT)
{
    __shared__ float lds[64 * 65];
    const int hwt = blockIdx.x;   // 0..15
    const int b   = blockIdx.y;   // 0..7
    const int tid = threadIdx.x;

    for (int kc = 0; kc < 6; ++kc) {
        for (int idx = tid; idx < 4096; idx += 256) {
            int cl = idx >> 6, hwl = idx & 63;
            lds[cl * 65 + hwl] = query[((size_t)b * NCn + kc * 64 + cl) * NQn + hwt * 64 + hwl];
        }
        __syncthreads();
        for (int idx = tid; idx < 4096; idx += 256) {
            int hwl = idx >> 6, cl = idx & 63;
            qXT[((size_t)b * NQn + hwt * 64 + hwl) * NCn + kc * 64 + cl] =
                f2bf(lds[cl * 65 + hwl]);
        }
        __syncthreads();
    }
}

// ---------------------------------------------------------------------------
// Kernel B: depthwise 3x3 stride2 + GELU + 1x1 (64->2) + tanh -> pixel coords
// ---------------------------------------------------------------------------
__global__ __launch_bounds__(256) void k_offsets(
    const float* __restrict__ t1, const float* __restrict__ w2,
    const float* __restrict__ b2, const float* __restrict__ w3,
    float* __restrict__ posb)
{
    const int wid  = blockIdx.x * 4 + (threadIdx.x >> 6);
    const int lane = threadIdx.x & 63;
    const int bg = wid / NSn, s = wid % NSn;
    const int hk = s / WKn, wk = s % WKn;

    const float* tp = t1 + (bg * 64 + lane) * NQn + (hk * 2) * Wn + wk * 2;
    const float* wp = w2 + lane * 9;
    float sv = b2[lane];
    #pragma unroll
    for (int i = 0; i < 3; ++i)
        #pragma unroll
        for (int j = 0; j < 3; ++j)
            sv += tp[i * Wn + j] * wp[i * 3 + j];
    float gv = gelu_f(sv);
    float ay = w3[lane] * gv;
    float ax = w3[64 + lane] * gv;
    #pragma unroll
    for (int off = 32; off > 0; off >>= 1) {
        ay += __shfl_xor(ay, off, 64);
        ax += __shfl_xor(ax, off, 64);
    }
    if (lane == 0) {
        float fy = tanhf(ay) * (2.0f / 14.0f);
        float fx = tanhf(ax) * (2.0f / 14.0f);
        float cy = (float)(hk * 2 + 1) * (2.0f / 31.0f) - 1.0f;
        float cx = (float)(wk * 2 + 1) * (2.0f / 31.0f) - 1.0f;
        float py = fminf(fmaxf(fy + cy, -1.0f), 1.0f);
        float px = fminf(fmaxf(fx + cx, -1.0f), 1.0f);
        posb[wid * 2 + 0] = (py + 1.0f) * 0.5f * 31.0f;
        posb[wid * 2 + 1] = (px + 1.0f) * 0.5f * 31.0f;
    }
}

// ---------------------------------------------------------------------------
// Kernel C: bilinear sampling -> smpT (8, 1024(pad), 384) bf16, n-major.
// ---------------------------------------------------------------------------
__global__ __launch_bounds__(256) void k_sample(
    const float* __restrict__ xr1, const float* __restrict__ xr2,
    const float* __restrict__ xx1, const float* __restrict__ xx2,
    const float* __restrict__ posb, ushort* __restrict__ smpT)
{
    const int bg = blockIdx.x;
    const int m  = blockIdx.y;
    const int b = bg / Gn, g = bg % Gn;
    const float* img = (m == 0) ? xr1 : (m == 1) ? xr2 : (m == 2) ? xx1 : xx2;

    for (int idx = threadIdx.x; idx < 64 * NSn; idx += 256) {
        int c = idx & 63, s = idx >> 6;
        float py = posb[(bg * NSn + s) * 2 + 0];
        float px = posb[(bg * NSn + s) * 2 + 1];
        float y0f = floorf(py), x0f = floorf(px);
        float wy = py - y0f, wx = px - x0f;
        int y0 = (int)y0f, x0 = (int)x0f;
        int y1 = min(y0 + 1, Hn - 1), x1 = min(x0 + 1, Wn - 1);
        const float* base = img + (b * NCn + g * GCn + c) * NQn;
        float v00 = base[y0 * Wn + x0], v01 = base[y0 * Wn + x1];
        float v10 = base[y1 * Wn + x0], v11 = base[y1 * Wn + x1];
        float v = v00 * (1.0f - wy) * (1.0f - wx) + v01 * (1.0f - wy) * wx
                + v10 * wy * (1.0f - wx) + v11 * wy * wx;
        smpT[((size_t)b * NQn + m * NSn + s) * NCn + g * GCn + c] = f2bf(v);
    }
}

// ---------------------------------------------------------------------------
// MFMA GEMM: C[b,m,n] = sum_k A[m,k] * XT[b,n,k]  (bf16 in, fp32 acc)
// grid (M/32, ceil(N/256), batch), 4 waves; wave tile 32m x 64n.
// modes: 0 fp32 (b,384,N)+resid | 2 bf16 (b,12,N,32) | 3 fp32+GELU (b,64,1024)
// ---------------------------------------------------------------------------
__global__ __launch_bounds__(256) void k_gemm(
    const ushort* __restrict__ A, const ushort* __restrict__ XT,
    const float* __restrict__ bias, const float* __restrict__ resid,
    float* __restrict__ Yf, ushort* __restrict__ Yh,
    int K, int Npad, int N, int mode)
{
    const int mb = blockIdx.x, nb = blockIdx.y, b = blockIdx.z;
    const int w = threadIdx.x >> 6, lane = threadIdx.x & 63;
    const int l16 = lane & 15, quad = lane >> 4;
    const int m0 = mb * 32;
    const int n0 = nb * 256 + w * 64;

    floatx4 zero = {0.0f, 0.0f, 0.0f, 0.0f};
    floatx4 acc[2][4] = {{zero, zero, zero, zero}, {zero, zero, zero, zero}};

    const ushort* a0 = A + (size_t)(m0 + l16) * K + quad * 8;
    const ushort* a1 = a0 + (size_t)16 * K;
    const ushort* bp = XT + ((size_t)b * Npad + n0 + l16) * K + quad * 8;

    #pragma unroll 2
    for (int k0 = 0; k0 < K; k0 += 32) {
        short8 af0 = *(const short8*)(a0 + k0);
        short8 af1 = *(const short8*)(a1 + k0);
        short8 bf[4];
        #pragma unroll
        for (int t = 0; t < 4; ++t)
            bf[t] = *(const short8*)(bp + (size_t)(t * 16) * K + k0);
        #pragma unroll
        for (int t = 0; t < 4; ++t) {
            acc[0][t] = __builtin_amdgcn_mfma_f32_16x16x32_bf16(af0, bf[t], acc[0][t], 0, 0, 0);
            acc[1][t] = __builtin_amdgcn_mfma_f32_16x16x32_bf16(af1, bf[t], acc[1][t], 0, 0, 0);
        }
    }

    // C-frag: m = m0 + a*16 + quad*4 + r ; n = n0 + t*16 + l16
    if (mode == 0) {
        #pragma unroll
        for (int a = 0; a < 2; ++a)
            #pragma unroll
            for (int r = 0; r < 4; ++r) {
                int m = m0 + a * 16 + quad * 4 + r;
                float bb = bias[m];
                #pragma unroll
                for (int t = 0; t < 4; ++t) {
                    int n = n0 + t * 16 + l16;
                    if (n < N) {
                        size_t o = ((size_t)b * NCn + m) * N + n;
                        Yf[o] = acc[a][t][r] + bb + resid[o];
                    }
                }
            }
    } else if (mode == 2) {
        #pragma unroll
        for (int a = 0; a < 2; ++a)
            #pragma unroll
            for (int r = 0; r < 4; ++r) {
                int m = m0 + a * 16 + quad * 4 + r;
                int head = m >> 5, d = m & 31;
                float bb = bias[m];
                #pragma unroll
                for (int t = 0; t < 4; ++t) {
                    int n = n0 + t * 16 + l16;
                    if (n < N)
                        Yh[((size_t)(b * HEADSn + head) * N + n) * 32 + d] =
                            f2bf(acc[a][t][r] + bb);
                }
            }
    } else {  // mode 3: GELU, out (b, 64, 1024) fp32
        #pragma unroll
        for (int a = 0; a < 2; ++a)
            #pragma unroll
            for (int r = 0; r < 4; ++r) {
                int m = m0 + a * 16 + quad * 4 + r;
                float bb = bias[m];
                #pragma unroll
                for (int t = 0; t < 4; ++t) {
                    int n = n0 + t * 16 + l16;
                    Yf[((size_t)b * 64 + m) * NQn + n] = gelu_f(acc[a][t][r] + bb);
                }
            }
    }
}

// ---------------------------------------------------------------------------
// Fused K+V projection (shared B-frags).
// K out: bf16 (b,12,900,32). V out: bf16 (b,384,VSTRIDE) d-major.
// V pad keys [900, VSTRIDE) are written as ZERO bf16 — vTb overlays stale
// fp32 t1 data whose bit pattern can decode as bf16 Inf/NaN; 0*Inf = NaN in
// the PV MFMA killed round 3. Every V element a fragment can read must be a
// finite bf16 we wrote.
// ---------------------------------------------------------------------------
__global__ __launch_bounds__(256) void k_gemm_kv(
    const ushort* __restrict__ Ak, const ushort* __restrict__ Av,
    const ushort* __restrict__ XT,
    const float* __restrict__ biask, const float* __restrict__ biasv,
    ushort* __restrict__ Yk, ushort* __restrict__ Yv)
{
    const int mb = blockIdx.x, nb = blockIdx.y, b = blockIdx.z;
    const int w = threadIdx.x >> 6, lane = threadIdx.x & 63;
    const int l16 = lane & 15, quad = lane >> 4;
    const int m0 = mb * 32;
    const int n0 = nb * 256 + w * 64;
    const int K = NCn;

    floatx4 zero = {0.0f, 0.0f, 0.0f, 0.0f};
    floatx4 acck[2][4] = {{zero, zero, zero, zero}, {zero, zero, zero, zero}};
    floatx4 accv[2][4] = {{zero, zero, zero, zero}, {zero, zero, zero, zero}};

    const ushort* ak0 = Ak + (size_t)(m0 + l16) * K + quad * 8;
    const ushort* av0 = Av + (size_t)(m0 + l16) * K + quad * 8;
    const ushort* bp  = XT + ((size_t)b * NQn + n0 + l16) * K + quad * 8;

    for (int k0 = 0; k0 < K; k0 += 32) {
        short8 afk0 = *(const short8*)(ak0 + k0);
        short8 afk1 = *(const short8*)(ak0 + (size_t)16 * K + k0);
        short8 afv0 = *(const short8*)(av0 + k0);
        short8 afv1 = *(const short8*)(av0 + (size_t)16 * K + k0);
        short8 bf[4];
        #pragma unroll
        for (int t = 0; t < 4; ++t)
            bf[t] = *(const short8*)(bp + (size_t)(t * 16) * K + k0);
        #pragma unroll
        for (int t = 0; t < 4; ++t) {
            acck[0][t] = __builtin_amdgcn_mfma_f32_16x16x32_bf16(afk0, bf[t], acck[0][t], 0, 0, 0);
            acck[1][t] = __builtin_amdgcn_mfma_f32_16x16x32_bf16(afk1, bf[t], acck[1][t], 0, 0, 0);
            accv[0][t] = __builtin_amdgcn_mfma_f32_16x16x32_bf16(afv0, bf[t], accv[0][t], 0, 0, 0);
            accv[1][t] = __builtin_amdgcn_mfma_f32_16x16x32_bf16(afv1, bf[t], accv[1][t], 0, 0, 0);
        }
    }

    #pragma unroll
    for (int a = 0; a < 2; ++a)
        #pragma unroll
        for (int r = 0; r < 4; ++r) {
            int m = m0 + a * 16 + quad * 4 + r;
            int head = m >> 5, d = m & 31;
            float bk = biask[m], bv = biasv[m];
            #pragma unroll
            for (int t = 0; t < 4; ++t) {
                int n = n0 + t * 16 + l16;
                if (n < NKVn)
                    Yk[((size_t)(b * HEADSn + head) * NKVn + n) * 32 + d] =
                        f2bf(acck[a][t][r] + bk);
                if (n < VSTRIDE)
                    Yv[((size_t)b * NCn + m) * VSTRIDE + n] =
                        (n < NKVn) ? f2bf(accv[a][t][r] + bv) : (ushort)0;
            }
        }
}

// ---------------------------------------------------------------------------
// Flash attention, bf16 MFMA. Output directly as bf16 X^T (b, 1024, 384).
// ---------------------------------------------------------------------------
__global__ __launch_bounds__(256) void k_attn_mfma(
    const ushort* __restrict__ qT, const ushort* __restrict__ kT,
    const ushort* __restrict__ vb, ushort* __restrict__ aoutT)
{
    __shared__ __align__(16) ushort p_lds[4 * 16 * 80];
    const int mt = blockIdx.x, h = blockIdx.y, b = blockIdx.z;
    const int tid = threadIdx.x;
    const int w = tid >> 6, lane = tid & 63;
    const int l16 = lane & 15, quad = lane >> 4;
    const int bh = b * HEADSn + h;
    const float scale = 0.17677669529663687f;

    ushort* p_w = p_lds + w * (16 * 80);

    const short8 qf = *(const short8*)(qT +
        (size_t)((bh * NQn + mt * 64 + w * 16 + l16) * 32 + quad * 8));

    floatx4 zero = {0.0f, 0.0f, 0.0f, 0.0f};
    floatx4 oacc[2] = {zero, zero};
    float lrun[4] = {0.0f, 0.0f, 0.0f, 0.0f};

    const ushort* kbase = kT + (size_t)bh * NKVn * 32;
    const ushort* vbase = vb + ((size_t)b * NCn + h * Dn) * VSTRIDE;

    for (int nc = 0; nc < 15; ++nc) {
        const int n0 = nc * 64;
        floatx4 sf[4];
        #pragma unroll
        for (int t = 0; t < 4; ++t) {
            const short8 kf = *(const short8*)(kbase +
                (size_t)((n0 + t * 16 + l16) * 32 + quad * 8));
            sf[t] = __builtin_amdgcn_mfma_f32_16x16x32_bf16(qf, kf, zero, 0, 0, 0);
        }
        const int limit = NKVn - n0;
        #pragma unroll
        for (int t = 0; t < 4; ++t) {
            const int col = t * 16 + l16;
            #pragma unroll
            for (int r = 0; r < 4; ++r) {
                float p = (col < limit) ? __expf(sf[t][r] * scale) : 0.0f;
                lrun[r] += p;
                p_w[(quad * 4 + r) * 80 + col] = f2bf(p);
            }
        }
        #pragma unroll
        for (int kc = 0; kc < 2; ++kc) {
            const short8 pf = *(const short8*)(p_w + l16 * 80 + kc * 32 + quad * 8);
            #pragma unroll
            for (int nt2 = 0; nt2 < 2; ++nt2) {
                const short8 vf = *(const short8*)(vbase +
                    (size_t)((nt2 * 16 + l16) * VSTRIDE + n0 + kc * 32 + quad * 8));
                oacc[nt2] = __builtin_amdgcn_mfma_f32_16x16x32_bf16(pf, vf, oacc[nt2], 0, 0, 0);
            }
        }
    }

    #pragma unroll
    for (int r = 0; r < 4; ++r) {
        float l = lrun[r];
        l += __shfl_xor(l, 1, 64);
        l += __shfl_xor(l, 2, 64);
        l += __shfl_xor(l, 4, 64);
        l += __shfl_xor(l, 8, 64);
        lrun[r] = 1.0f / l;
    }

    // C-frag of O: query m = w*16 + quad*4 + r, dim d = nt2*16 + l16
    #pragma unroll
    for (int nt2 = 0; nt2 < 2; ++nt2)
        #pragma unroll
        for (int r = 0; r < 4; ++r) {
            int m = mt * 64 + w * 16 + quad * 4 + r;
            int d = h * Dn + nt2 * 16 + l16;
            aoutT[((size_t)b * NQn + m) * NCn + d] = f2bf(oacc[nt2][r] * lrun[r]);
        }
}

// ---------------------------------------------------------------------------
extern "C" void kernel_launch(void* const* d_in, const int* in_sizes, int n_in,
                              void* d_out, int out_size, void* d_ws, size_t ws_size,
                              hipStream_t stream) {
    const float* query = (const float*)d_in[0];
    const float* xr1   = (const float*)d_in[1];
    const float* xr2   = (const float*)d_in[2];
    const float* xx1   = (const float*)d_in[3];
    const float* xx2   = (const float*)d_in[4];
    const float* w1    = (const float*)d_in[5];
    const float* b1    = (const float*)d_in[6];
    const float* w2    = (const float*)d_in[7];
    const float* b2    = (const float*)d_in[8];
    const float* w3    = (const float*)d_in[9];
    const float* q_w   = (const float*)d_in[10];
    const float* q_b   = (const float*)d_in[11];
    const float* k_w   = (const float*)d_in[12];
    const float* k_b   = (const float*)d_in[13];
    const float* v_w   = (const float*)d_in[14];
    const float* v_b   = (const float*)d_in[15];
    const float* o_w   = (const float*)d_in[16];
    const float* o_b   = (const float*)d_in[17];
    float* out = (float*)d_out;

    // ---- workspace layout (float units), with liveness overlap ----
    float* ws = (float*)d_ws;
    // region A: dataT (dead after offconv gemm) overlaid by qXT/qTb/aoutT
    ushort* dataT = (ushort*)ws;                   // 48*1024*256 u = 6,291,456 f
    ushort* qXT   = (ushort*)ws;                   // 8*1024*384  u = 1,572,864 f
    ushort* qTb   = (ushort*)(ws + 1572864);       // 8*12*1024*32 u = 1,572,864 f
    ushort* aoutT = (ushort*)(ws + 3145728);       // 8*1024*384  u = 1,572,864 f
    // region B: t1 (dead after k_offsets) overlaid by kTb/vTb
    float*  t1    = ws + 6291456;                  // 48*64*1024 = 3,145,728 f
    ushort* kTb   = (ushort*)(ws + 6291456);       // 8*12*900*32 u = 1,382,400 f
    ushort* vTb   = (ushort*)(ws + 7673856);       // 8*384*960 u = 1,474,560 f -> ends 9,148,416
    // region C
    float*  posb  = ws + 9437184;                  // 21,600 -> pad 21,632
    ushort* smpT  = (ushort*)(ws + 9458816);       // 8*1024*384 u = 1,572,864 f
    ushort* wb    = (ushort*)(ws + 11031680);      // 606,208 u
    ushort* w1b = wb;
    ushort* qwb = wb + 16384;
    ushort* kwb = wb + 163840;
    ushort* vwb = wb + 311296;
    ushort* owb = wb + 458752;

    k_cvtw<<<dim3(2368), 256, 0, stream>>>(w1, q_w, k_w, v_w, o_w, wb);
    k_transpose4<<<dim3(16, 48), 256, 0, stream>>>(xr1, xr2, xx1, xx2, dataT);
    k_gemm<<<dim3(2, 4, 48), 256, 0, stream>>>(w1b, dataT, b1, nullptr,
                                               t1, nullptr, 256, NQn, NQn, 3);
    k_offsets<<<dim3(2700), 256, 0, stream>>>(t1, w2, b2, w3, posb);
    k_sample<<<dim3(48, 4), 256, 0, stream>>>(xr1, xr2, xx1, xx2, posb, smpT);
    k_transposeQ<<<dim3(16, Bn), 256, 0, stream>>>(query, qXT);
    k_gemm<<<dim3(12, 4, Bn), 256, 0, stream>>>(qwb, qXT, q_b, nullptr,
                                                nullptr, qTb, NCn, NQn, NQn, 2);
    k_gemm_kv<<<dim3(12, 4, Bn), 256, 0, stream>>>(kwb, vwb, smpT, k_b, v_b, kTb, vTb);
    k_attn_mfma<<<dim3(16, HEADSn, Bn), 256, 0, stream>>>(qTb, kTb, vTb, aoutT);
    k_gemm<<<dim3(12, 4, Bn), 256, 0, stream>>>(owb, aoutT, o_b, query,
                                                out, nullptr, NCn, NQn, NQn, 0);
}

// Round 5
// 332.998 us; speedup vs baseline: 3.0470x; 1.1560x over previous
//
#include <hip/hip_runtime.h>
#include <math.h>

#define Bn 8
#define NCn 384
#define Hn 32
#define Wn 32
#define Gn 6
#define GCn 64
#define HEADSn 12
#define Dn 32
#define HKn 15
#define WKn 15
#define NSn 225
#define NQn 1024
#define NKVn 900
#define VSTRIDE 960   // V row stride in bf16; covers max frag read (key 952+8) so
                      // no read leaves the row; keys 900..959 zero-filled.

typedef __attribute__((ext_vector_type(8))) short short8;
typedef __attribute__((ext_vector_type(4))) float floatx4;

__device__ __forceinline__ float gelu_f(float x) {
    return 0.5f * x * (1.0f + erff(x * 0.70710678118654752f));
}

__device__ __forceinline__ ushort f2bf(float x) {
    unsigned u = __float_as_uint(x);
    u = (u + 0x7FFF + ((u >> 16) & 1)) >> 16;   // RNE
    return (ushort)u;
}

// cheap round-half-up bf16 pack (for the hot P path; <= 1 ulp vs RNE)
__device__ __forceinline__ ushort f2bf_fast(float x) {
    return (ushort)((__float_as_uint(x) + 0x8000u) >> 16);
}

// ---------------------------------------------------------------------------
// Convert all weight matrices to bf16 (once per call; cheap).
// wb: w1b[16384] | qwb[147456] | kwb[147456] | vwb[147456] | owb[147456]
// ---------------------------------------------------------------------------
__global__ __launch_bounds__(256) void k_cvtw(
    const float* __restrict__ w1, const float* __restrict__ qw,
    const float* __restrict__ kw, const float* __restrict__ vw,
    const float* __restrict__ ow, ushort* __restrict__ wb)
{
    int i = blockIdx.x * 256 + threadIdx.x;
    if (i >= 606208) return;
    float v;
    if      (i < 16384)  v = w1[i];
    else if (i < 163840) v = qw[i - 16384];
    else if (i < 311296) v = kw[i - 163840];
    else if (i < 458752) v = vw[i - 311296];
    else                 v = ow[i - 458752];
    wb[i] = f2bf(v);
}

// ---------------------------------------------------------------------------
// Build dataT (48, 1024, 256) bf16: n-major, c-contiguous view of the
// 4-map concat split into groups. LDS-transposed 64x64 tiles.
// ---------------------------------------------------------------------------
__global__ __launch_bounds__(256) void k_transpose4(
    const float* __restrict__ xr1, const float* __restrict__ xr2,
    const float* __restrict__ xx1, const float* __restrict__ xx2,
    ushort* __restrict__ dataT)
{
    __shared__ float lds[64 * 65];
    const int hwt = blockIdx.x;   // 0..15
    const int bg  = blockIdx.y;   // 0..47
    const int b = bg / Gn, g = bg % Gn;
    const int tid = threadIdx.x;

    for (int kc = 0; kc < 4; ++kc) {
        for (int idx = tid; idx < 4096; idx += 256) {
            int cl = idx >> 6, hwl = idx & 63;
            int gch = g * 256 + kc * 64 + cl;
            int m = gch / NCn, cm = gch % NCn;
            const float* img = (m == 0) ? xr1 : (m == 1) ? xr2 : (m == 2) ? xx1 : xx2;
            lds[cl * 65 + hwl] = img[(b * NCn + cm) * NQn + hwt * 64 + hwl];
        }
        __syncthreads();
        for (int idx = tid; idx < 4096; idx += 256) {
            int hwl = idx >> 6, cl = idx & 63;
            dataT[((size_t)bg * NQn + hwt * 64 + hwl) * 256 + kc * 64 + cl] =
                f2bf(lds[cl * 65 + hwl]);
        }
        __syncthreads();
    }
}

// ---------------------------------------------------------------------------
// Build qXT (8, 1024, 384) bf16 from query (8, 384, 1024) fp32.
// ---------------------------------------------------------------------------
__global__ __launch_bounds__(256) void k_transposeQ(
    const float* __restrict__ query, ushort* __restrict__ qXT)
{
    __shared__ float lds[64 * 65];
    const int hwt = blockIdx.x;   // 0..15
    const int b   = blockIdx.y;   // 0..7
    const int tid = threadIdx.x;

    for (int kc = 0; kc < 6; ++kc) {
        for (int idx = tid; idx < 4096; idx += 256) {
            int cl = idx >> 6, hwl = idx & 63;
            lds[cl * 65 + hwl] = query[((size_t)b * NCn + kc * 64 + cl) * NQn + hwt * 64 + hwl];
        }
        __syncthreads();
        for (int idx = tid; idx < 4096; idx += 256) {
            int hwl = idx >> 6, cl = idx & 63;
            qXT[((size_t)b * NQn + hwt * 64 + hwl) * NCn + kc * 64 + cl] =
                f2bf(lds[cl * 65 + hwl]);
        }
        __syncthreads();
    }
}

// ---------------------------------------------------------------------------
// Kernel B: depthwise 3x3 stride2 + GELU + 1x1 (64->2) + tanh -> pixel coords
// ---------------------------------------------------------------------------
__global__ __launch_bounds__(256) void k_offsets(
    const float* __restrict__ t1, const float* __restrict__ w2,
    const float* __restrict__ b2, const float* __restrict__ w3,
    float* __restrict__ posb)
{
    const int wid  = blockIdx.x * 4 + (threadIdx.x >> 6);
    const int lane = threadIdx.x & 63;
    const int bg = wid / NSn, s = wid % NSn;
    const int hk = s / WKn, wk = s % WKn;

    const float* tp = t1 + (bg * 64 + lane) * NQn + (hk * 2) * Wn + wk * 2;
    const float* wp = w2 + lane * 9;
    float sv = b2[lane];
    #pragma unroll
    for (int i = 0; i < 3; ++i)
        #pragma unroll
        for (int j = 0; j < 3; ++j)
            sv += tp[i * Wn + j] * wp[i * 3 + j];
    float gv = gelu_f(sv);
    float ay = w3[lane] * gv;
    float ax = w3[64 + lane] * gv;
    #pragma unroll
    for (int off = 32; off > 0; off >>= 1) {
        ay += __shfl_xor(ay, off, 64);
        ax += __shfl_xor(ax, off, 64);
    }
    if (lane == 0) {
        float fy = tanhf(ay) * (2.0f / 14.0f);
        float fx = tanhf(ax) * (2.0f / 14.0f);
        float cy = (float)(hk * 2 + 1) * (2.0f / 31.0f) - 1.0f;
        float cx = (float)(wk * 2 + 1) * (2.0f / 31.0f) - 1.0f;
        float py = fminf(fmaxf(fy + cy, -1.0f), 1.0f);
        float px = fminf(fmaxf(fx + cx, -1.0f), 1.0f);
        posb[wid * 2 + 0] = (py + 1.0f) * 0.5f * 31.0f;
        posb[wid * 2 + 1] = (px + 1.0f) * 0.5f * 31.0f;
    }
}

// ---------------------------------------------------------------------------
// Kernel C: bilinear sampling -> smpT (8, 1024(pad), 384) bf16, n-major.
// ---------------------------------------------------------------------------
__global__ __launch_bounds__(256) void k_sample(
    const float* __restrict__ xr1, const float* __restrict__ xr2,
    const float* __restrict__ xx1, const float* __restrict__ xx2,
    const float* __restrict__ posb, ushort* __restrict__ smpT)
{
    const int bg = blockIdx.x;
    const int m  = blockIdx.y;
    const int b = bg / Gn, g = bg % Gn;
    const float* img = (m == 0) ? xr1 : (m == 1) ? xr2 : (m == 2) ? xx1 : xx2;

    for (int idx = threadIdx.x; idx < 64 * NSn; idx += 256) {
        int c = idx & 63, s = idx >> 6;
        float py = posb[(bg * NSn + s) * 2 + 0];
        float px = posb[(bg * NSn + s) * 2 + 1];
        float y0f = floorf(py), x0f = floorf(px);
        float wy = py - y0f, wx = px - x0f;
        int y0 = (int)y0f, x0 = (int)x0f;
        int y1 = min(y0 + 1, Hn - 1), x1 = min(x0 + 1, Wn - 1);
        const float* base = img + (b * NCn + g * GCn + c) * NQn;
        float v00 = base[y0 * Wn + x0], v01 = base[y0 * Wn + x1];
        float v10 = base[y1 * Wn + x0], v11 = base[y1 * Wn + x1];
        float v = v00 * (1.0f - wy) * (1.0f - wx) + v01 * (1.0f - wy) * wx
                + v10 * wy * (1.0f - wx) + v11 * wy * wx;
        smpT[((size_t)b * NQn + m * NSn + s) * NCn + g * GCn + c] = f2bf(v);
    }
}

// ---------------------------------------------------------------------------
// MFMA GEMM: C[b,m,n] = sum_k A[m,k] * XT[b,n,k]  (bf16 in, fp32 acc)
// grid (ceil(N/256), M/32, batch): x=nb so blocks sharing an XT tile land on
// few XCDs (dispatch id = nb + 4*mb + ... ; 4*mb mod 8 in {0,4} -> 2 XCDs/tile).
// 4 waves; wave tile 32m x 64n.
// modes: 0 fp32 (b,384,N)+resid | 3 fp32+GELU (b,64,1024)
// ---------------------------------------------------------------------------
__global__ __launch_bounds__(256) void k_gemm(
    const ushort* __restrict__ A, const ushort* __restrict__ XT,
    const float* __restrict__ bias, const float* __restrict__ resid,
    float* __restrict__ Yf,
    int K, int Npad, int N, int mode)
{
    const int nb = blockIdx.x, mb = blockIdx.y, b = blockIdx.z;
    const int w = threadIdx.x >> 6, lane = threadIdx.x & 63;
    const int l16 = lane & 15, quad = lane >> 4;
    const int m0 = mb * 32;
    const int n0 = nb * 256 + w * 64;

    floatx4 zero = {0.0f, 0.0f, 0.0f, 0.0f};
    floatx4 acc[2][4] = {{zero, zero, zero, zero}, {zero, zero, zero, zero}};

    const ushort* a0 = A + (size_t)(m0 + l16) * K + quad * 8;
    const ushort* a1 = a0 + (size_t)16 * K;
    const ushort* bp = XT + ((size_t)b * Npad + n0 + l16) * K + quad * 8;

    #pragma unroll 2
    for (int k0 = 0; k0 < K; k0 += 32) {
        short8 af0 = *(const short8*)(a0 + k0);
        short8 af1 = *(const short8*)(a1 + k0);
        short8 bf[4];
        #pragma unroll
        for (int t = 0; t < 4; ++t)
            bf[t] = *(const short8*)(bp + (size_t)(t * 16) * K + k0);
        #pragma unroll
        for (int t = 0; t < 4; ++t) {
            acc[0][t] = __builtin_amdgcn_mfma_f32_16x16x32_bf16(af0, bf[t], acc[0][t], 0, 0, 0);
            acc[1][t] = __builtin_amdgcn_mfma_f32_16x16x32_bf16(af1, bf[t], acc[1][t], 0, 0, 0);
        }
    }

    // C-frag: m = m0 + a*16 + quad*4 + r ; n = n0 + t*16 + l16
    if (mode == 0) {
        #pragma unroll
        for (int a = 0; a < 2; ++a)
            #pragma unroll
            for (int r = 0; r < 4; ++r) {
                int m = m0 + a * 16 + quad * 4 + r;
                float bb = bias[m];
                #pragma unroll
                for (int t = 0; t < 4; ++t) {
                    int n = n0 + t * 16 + l16;
                    if (n < N) {
                        size_t o = ((size_t)b * NCn + m) * N + n;
                        Yf[o] = acc[a][t][r] + bb + resid[o];
                    }
                }
            }
    } else {  // mode 3: GELU, out (b, 64, 1024) fp32
        #pragma unroll
        for (int a = 0; a < 2; ++a)
            #pragma unroll
            for (int r = 0; r < 4; ++r) {
                int m = m0 + a * 16 + quad * 4 + r;
                float bb = bias[m];
                #pragma unroll
                for (int t = 0; t < 4; ++t) {
                    int n = n0 + t * 16 + l16;
                    Yf[((size_t)b * 64 + m) * NQn + n] = gelu_f(acc[a][t][r] + bb);
                }
            }
    }
}

// ---------------------------------------------------------------------------
// Fused Q + K + V projections in ONE launch (768 blocks -> 3 blocks/CU,
// double the resident waves of two 384-block launches; latency-bound regime).
// z < 8:  Q path, batch z:  qTb (b,12,1024,32) bf16
// z >= 8: KV path, batch z-8: kTb (b,12,900,32), vTb (b,384,VSTRIDE) zero-pad
// ---------------------------------------------------------------------------
__global__ __launch_bounds__(256) void k_gemm_qkv(
    const ushort* __restrict__ qwb, const ushort* __restrict__ kwb,
    const ushort* __restrict__ vwb,
    const ushort* __restrict__ qXT, const ushort* __restrict__ smpT,
    const float* __restrict__ q_b, const float* __restrict__ k_b,
    const float* __restrict__ v_b,
    ushort* __restrict__ qTb, ushort* __restrict__ kTb, ushort* __restrict__ vTb)
{
    const int nb = blockIdx.x, mb = blockIdx.y;
    const int w = threadIdx.x >> 6, lane = threadIdx.x & 63;
    const int l16 = lane & 15, quad = lane >> 4;
    const int m0 = mb * 32;
    const int n0 = nb * 256 + w * 64;
    const int K = NCn;
    floatx4 zero = {0.0f, 0.0f, 0.0f, 0.0f};

    if (blockIdx.z < Bn) {
        const int b = blockIdx.z;
        floatx4 acc[2][4] = {{zero, zero, zero, zero}, {zero, zero, zero, zero}};
        const ushort* a0 = qwb + (size_t)(m0 + l16) * K + quad * 8;
        const ushort* a1 = a0 + (size_t)16 * K;
        const ushort* bp = qXT + ((size_t)b * NQn + n0 + l16) * K + quad * 8;

        #pragma unroll 2
        for (int k0 = 0; k0 < K; k0 += 32) {
            short8 af0 = *(const short8*)(a0 + k0);
            short8 af1 = *(const short8*)(a1 + k0);
            short8 bf[4];
            #pragma unroll
            for (int t = 0; t < 4; ++t)
                bf[t] = *(const short8*)(bp + (size_t)(t * 16) * K + k0);
            #pragma unroll
            for (int t = 0; t < 4; ++t) {
                acc[0][t] = __builtin_amdgcn_mfma_f32_16x16x32_bf16(af0, bf[t], acc[0][t], 0, 0, 0);
                acc[1][t] = __builtin_amdgcn_mfma_f32_16x16x32_bf16(af1, bf[t], acc[1][t], 0, 0, 0);
            }
        }
        #pragma unroll
        for (int a = 0; a < 2; ++a)
            #pragma unroll
            for (int r = 0; r < 4; ++r) {
                int m = m0 + a * 16 + quad * 4 + r;
                int head = m >> 5, d = m & 31;
                float bb = q_b[m];
                #pragma unroll
                for (int t = 0; t < 4; ++t) {
                    int n = n0 + t * 16 + l16;   // always < 1024
                    qTb[((size_t)(b * HEADSn + head) * NQn + n) * 32 + d] =
                        f2bf(acc[a][t][r] + bb);
                }
            }
    } else {
        const int b = blockIdx.z - Bn;
        floatx4 acck[2][4] = {{zero, zero, zero, zero}, {zero, zero, zero, zero}};
        floatx4 accv[2][4] = {{zero, zero, zero, zero}, {zero, zero, zero, zero}};
        const ushort* ak0 = kwb + (size_t)(m0 + l16) * K + quad * 8;
        const ushort* av0 = vwb + (size_t)(m0 + l16) * K + quad * 8;
        const ushort* bp  = smpT + ((size_t)b * NQn + n0 + l16) * K + quad * 8;

        for (int k0 = 0; k0 < K; k0 += 32) {
            short8 afk0 = *(const short8*)(ak0 + k0);
            short8 afk1 = *(const short8*)(ak0 + (size_t)16 * K + k0);
            short8 afv0 = *(const short8*)(av0 + k0);
            short8 afv1 = *(const short8*)(av0 + (size_t)16 * K + k0);
            short8 bf[4];
            #pragma unroll
            for (int t = 0; t < 4; ++t)
                bf[t] = *(const short8*)(bp + (size_t)(t * 16) * K + k0);
            #pragma unroll
            for (int t = 0; t < 4; ++t) {
                acck[0][t] = __builtin_amdgcn_mfma_f32_16x16x32_bf16(afk0, bf[t], acck[0][t], 0, 0, 0);
                acck[1][t] = __builtin_amdgcn_mfma_f32_16x16x32_bf16(afk1, bf[t], acck[1][t], 0, 0, 0);
                accv[0][t] = __builtin_amdgcn_mfma_f32_16x16x32_bf16(afv0, bf[t], accv[0][t], 0, 0, 0);
                accv[1][t] = __builtin_amdgcn_mfma_f32_16x16x32_bf16(afv1, bf[t], accv[1][t], 0, 0, 0);
            }
        }
        #pragma unroll
        for (int a = 0; a < 2; ++a)
            #pragma unroll
            for (int r = 0; r < 4; ++r) {
                int m = m0 + a * 16 + quad * 4 + r;
                int head = m >> 5, d = m & 31;
                float bk = k_b[m], bv = v_b[m];
                #pragma unroll
                for (int t = 0; t < 4; ++t) {
                    int n = n0 + t * 16 + l16;
                    if (n < NKVn)
                        kTb[((size_t)(b * HEADSn + head) * NKVn + n) * 32 + d] =
                            f2bf(acck[a][t][r] + bk);
                    if (n < VSTRIDE)
                        vTb[((size_t)b * NCn + m) * VSTRIDE + n] =
                            (n < NKVn) ? f2bf(accv[a][t][r] + bv) : (ushort)0;
                }
            }
    }
}

// ---------------------------------------------------------------------------
// Flash attention, bf16 MFMA. 32 queries/wave (2 Q-frags), software-prefetched
// K/V frags, XCD-local grid (x = b*12+h so all mt-blocks of a head share an
// XCD L2), wave-uniform masked-tail branch. Output bf16 X^T (b, 1024, 384).
// ---------------------------------------------------------------------------
__global__ __launch_bounds__(256) void k_attn_mfma(
    const ushort* __restrict__ qT, const ushort* __restrict__ kT,
    const ushort* __restrict__ vb, ushort* __restrict__ aoutT)
{
    __shared__ __align__(16) ushort p_lds[4 * 2 * 16 * 80];   // 20.5 KB
    const int bh = blockIdx.x;        // 0..95
    const int mt = blockIdx.y;        // 0..7  (128 queries/block)
    const int b = bh / HEADSn, h = bh % HEADSn;
    const int tid = threadIdx.x;
    const int w = tid >> 6, lane = tid & 63;
    const int l16 = lane & 15, quad = lane >> 4;
    const float cexp = 0.25503486f;   // (1/sqrt(32)) * log2(e)

    ushort* p_w[2] = { p_lds + (w * 2 + 0) * (16 * 80),
                       p_lds + (w * 2 + 1) * (16 * 80) };

    const int q0 = mt * 128 + w * 32;
    short8 qf[2];
    qf[0] = *(const short8*)(qT + (size_t)((bh * NQn + q0 + l16) * 32 + quad * 8));
    qf[1] = *(const short8*)(qT + (size_t)((bh * NQn + q0 + 16 + l16) * 32 + quad * 8));

    const ushort* kbase = kT + (size_t)bh * NKVn * 32;
    const ushort* vbase = vb + ((size_t)b * NCn + h * Dn) * VSTRIDE;

    floatx4 zero = {0.0f, 0.0f, 0.0f, 0.0f};
    floatx4 oacc[2][2] = {{zero, zero}, {zero, zero}};
    float lrun[2][4] = {};

    // K frags for chunk 0 (prefetched before the loop)
    short8 kf[4];
    #pragma unroll
    for (int t = 0; t < 4; ++t)
        kf[t] = *(const short8*)(kbase + (size_t)((t * 16 + l16) * 32 + quad * 8));

    for (int nc = 0; nc < 15; ++nc) {
        const int n0 = nc * 64;
        // V prefetch: used at the very end of this iteration
        short8 vf[2][2];
        #pragma unroll
        for (int kc = 0; kc < 2; ++kc)
            #pragma unroll
            for (int nt2 = 0; nt2 < 2; ++nt2)
                vf[kc][nt2] = *(const short8*)(vbase +
                    (size_t)((nt2 * 16 + l16) * VSTRIDE + n0 + kc * 32 + quad * 8));

        // QK^T: 8 independent MFMAs
        floatx4 sf[2][4];
        #pragma unroll
        for (int a = 0; a < 2; ++a)
            #pragma unroll
            for (int t = 0; t < 4; ++t)
                sf[a][t] = __builtin_amdgcn_mfma_f32_16x16x32_bf16(qf[a], kf[t], zero, 0, 0, 0);

        // K prefetch for chunk nc+1 (kf regs dead after QK issue)
        if (nc < 14) {
            #pragma unroll
            for (int t = 0; t < 4; ++t)
                kf[t] = *(const short8*)(kbase +
                    (size_t)((n0 + 64 + t * 16 + l16) * 32 + quad * 8));
        }

        // softmax (no max-subtraction; scores are small) + pack to LDS
        if (n0 + 64 <= NKVn) {
            #pragma unroll
            for (int a = 0; a < 2; ++a)
                #pragma unroll
                for (int t = 0; t < 4; ++t)
                    #pragma unroll
                    for (int r = 0; r < 4; ++r) {
                        float p = exp2f(sf[a][t][r] * cexp);
                        lrun[a][r] += p;
                        p_w[a][(quad * 4 + r) * 80 + t * 16 + l16] = f2bf_fast(p);
                    }
        } else {
            const int limit = NKVn - n0;   // 4 on the last chunk
            #pragma unroll
            for (int a = 0; a < 2; ++a)
                #pragma unroll
                for (int t = 0; t < 4; ++t) {
                    const int col = t * 16 + l16;
                    #pragma unroll
                    for (int r = 0; r < 4; ++r) {
                        float p = (col < limit) ? exp2f(sf[a][t][r] * cexp) : 0.0f;
                        lrun[a][r] += p;
                        p_w[a][(quad * 4 + r) * 80 + col] = f2bf_fast(p);
                    }
                }
        }

        // PV: same-wave LDS RAW (compiler inserts lgkmcnt waits; DS is in-order)
        #pragma unroll
        for (int a = 0; a < 2; ++a)
            #pragma unroll
            for (int kc = 0; kc < 2; ++kc) {
                const short8 pf = *(const short8*)(p_w[a] + l16 * 80 + kc * 32 + quad * 8);
                #pragma unroll
                for (int nt2 = 0; nt2 < 2; ++nt2)
                    oacc[a][nt2] = __builtin_amdgcn_mfma_f32_16x16x32_bf16(
                        pf, vf[kc][nt2], oacc[a][nt2], 0, 0, 0);
            }
    }

    // row-wise denominators (sum spread over the 16 l16 lanes of each quad)
    #pragma unroll
    for (int a = 0; a < 2; ++a)
        #pragma unroll
        for (int r = 0; r < 4; ++r) {
            float l = lrun[a][r];
            l += __shfl_xor(l, 1, 64);
            l += __shfl_xor(l, 2, 64);
            l += __shfl_xor(l, 4, 64);
            l += __shfl_xor(l, 8, 64);
            lrun[a][r] = 1.0f / l;
        }

    // C-frag of O: query m = q0 + a*16 + quad*4 + r, dim d = nt2*16 + l16
    #pragma unroll
    for (int a = 0; a < 2; ++a)
        #pragma unroll
        for (int nt2 = 0; nt2 < 2; ++nt2)
            #pragma unroll
            for (int r = 0; r < 4; ++r) {
                int m = q0 + a * 16 + quad * 4 + r;
                int d = h * Dn + nt2 * 16 + l16;
                aoutT[((size_t)b * NQn + m) * NCn + d] =
                    f2bf(oacc[a][nt2][r] * lrun[a][r]);
            }
}

// ---------------------------------------------------------------------------
extern "C" void kernel_launch(void* const* d_in, const int* in_sizes, int n_in,
                              void* d_out, int out_size, void* d_ws, size_t ws_size,
                              hipStream_t stream) {
    const float* query = (const float*)d_in[0];
    const float* xr1   = (const float*)d_in[1];
    const float* xr2   = (const float*)d_in[2];
    const float* xx1   = (const float*)d_in[3];
    const float* xx2   = (const float*)d_in[4];
    const float* w1    = (const float*)d_in[5];
    const float* b1    = (const float*)d_in[6];
    const float* w2    = (const float*)d_in[7];
    const float* b2    = (const float*)d_in[8];
    const float* w3    = (const float*)d_in[9];
    const float* q_w   = (const float*)d_in[10];
    const float* q_b   = (const float*)d_in[11];
    const float* k_w   = (const float*)d_in[12];
    const float* k_b   = (const float*)d_in[13];
    const float* v_w   = (const float*)d_in[14];
    const float* v_b   = (const float*)d_in[15];
    const float* o_w   = (const float*)d_in[16];
    const float* o_b   = (const float*)d_in[17];
    float* out = (float*)d_out;

    // ---- workspace layout (float units), with liveness overlap ----
    float* ws = (float*)d_ws;
    // region A: dataT (dead after offconv gemm) overlaid by qXT/qTb/aoutT
    ushort* dataT = (ushort*)ws;                   // 48*1024*256 u = 6,291,456 f
    ushort* qXT   = (ushort*)ws;                   // 8*1024*384  u = 1,572,864 f
    ushort* qTb   = (ushort*)(ws + 1572864);       // 8*12*1024*32 u = 1,572,864 f
    ushort* aoutT = (ushort*)(ws + 3145728);       // 8*1024*384  u = 1,572,864 f
    // region B: t1 (dead after k_offsets) overlaid by kTb/vTb
    float*  t1    = ws + 6291456;                  // 48*64*1024 = 3,145,728 f
    ushort* kTb   = (ushort*)(ws + 6291456);       // 8*12*900*32 u = 1,382,400 f
    ushort* vTb   = (ushort*)(ws + 7673856);       // 8*384*960 u = 1,474,560 f -> ends 9,148,416
    // region C
    float*  posb  = ws + 9437184;                  // 21,600 -> pad 21,632
    ushort* smpT  = (ushort*)(ws + 9458816);       // 8*1024*384 u = 1,572,864 f
    ushort* wb    = (ushort*)(ws + 11031680);      // 606,208 u
    ushort* w1b = wb;
    ushort* qwb = wb + 16384;
    ushort* kwb = wb + 163840;
    ushort* vwb = wb + 311296;
    ushort* owb = wb + 458752;

    k_cvtw<<<dim3(2368), 256, 0, stream>>>(w1, q_w, k_w, v_w, o_w, wb);
    k_transpose4<<<dim3(16, 48), 256, 0, stream>>>(xr1, xr2, xx1, xx2, dataT);
    k_gemm<<<dim3(4, 2, 48), 256, 0, stream>>>(w1b, dataT, b1, nullptr,
                                               t1, 256, NQn, NQn, 3);
    k_offsets<<<dim3(2700), 256, 0, stream>>>(t1, w2, b2, w3, posb);
    k_sample<<<dim3(48, 4), 256, 0, stream>>>(xr1, xr2, xx1, xx2, posb, smpT);
    k_transposeQ<<<dim3(16, Bn), 256, 0, stream>>>(query, qXT);
    k_gemm_qkv<<<dim3(4, 12, 16), 256, 0, stream>>>(qwb, kwb, vwb, qXT, smpT,
                                                    q_b, k_b, v_b, qTb, kTb, vTb);
    k_attn_mfma<<<dim3(96, 8), 256, 0, stream>>>(qTb, kTb, vTb, aoutT);
    k_gemm<<<dim3(4, 12, Bn), 256, 0, stream>>>(owb, aoutT, o_b, query,
                                                out, NCn, NQn, NQn, 0);
}